// Round 19
// baseline (941.117 us; speedup 1.0000x reference)
//
#include <hip/hip_runtime.h>
#include <hip/hip_bf16.h>
#include <cstdint>

typedef unsigned short u16;
typedef unsigned int u32;
typedef __attribute__((ext_vector_type(4))) float f32x4;
typedef __attribute__((ext_vector_type(8))) __bf16 bf16x8;

#define DEVFN static __device__ __forceinline__

constexpr int Bb = 4, S = 2048, Dm = 2048, H = 16, DH = 128;
constexpr int M  = Bb * S;   // 8192 rows
constexpr int N3 = 3 * Dm;   // 6144
constexpr int KK = 2048;     // K for both GEMMs
constexpr float ATTN_SCALE = 0.088388347648318447f;  // 1/sqrt(128)
constexpr float LOG2E = 1.4426950408889634f;

DEVFN u16 f2bf(float f) {
  union { float f; u32 u; } v; v.f = f;
  u32 u = v.u;
  return (u16)((u + 0x7fffu + ((u >> 16) & 1u)) >> 16);
}

DEVFN void async16(const void* g, void* l) {
  __builtin_amdgcn_global_load_lds(
      (__attribute__((address_space(1))) unsigned int*)(g),
      (__attribute__((address_space(3))) unsigned int*)(l), 16, 0, 0);
}

// ---------------- fused prep kernel ----------------

DEVFN void transpose_tile(const float* __restrict__ in, u16* __restrict__ out,
                          int R, int C, int bx, int by, int tid) {
  __shared__ float tile[32][33];
  int c0 = bx * 32, r0 = by * 32;
  int tx = tid & 31, ty = tid >> 5;  // 32 x 8
#pragma unroll
  for (int i = 0; i < 4; i++)
    tile[ty + 8 * i][tx] = in[(size_t)(r0 + ty + 8 * i) * C + c0 + tx];
  __syncthreads();
  int tx2 = (tid & 7) * 4, ty2 = tid >> 3;
  ushort4 o;
  o.x = f2bf(tile[tx2 + 0][ty2]);
  o.y = f2bf(tile[tx2 + 1][ty2]);
  o.z = f2bf(tile[tx2 + 2][ty2]);
  o.w = f2bf(tile[tx2 + 3][ty2]);
  *(ushort4*)(&out[(size_t)(c0 + ty2) * R + r0 + tx2]) = o;
}

__global__ __launch_bounds__(256) void k_prep(
    const float* __restrict__ x, const float* __restrict__ w_qkv,
    const float* __restrict__ w_out, u16* __restrict__ x_bf,
    u16* __restrict__ wqkvT, u16* __restrict__ woutT) {
  const int bid = blockIdx.x, tid = threadIdx.x;
  constexpr int NB_CVT = (M * Dm) / 1024;            // 16384
  constexpr int NB_T1 = (N3 / 32) * (Dm / 32);       // 12288
  if (bid < NB_CVT) {
    int i = (bid * 256 + tid) * 4;
    float4 f = *(const float4*)(x + i);
    ushort4 o;
    o.x = f2bf(f.x); o.y = f2bf(f.y); o.z = f2bf(f.z); o.w = f2bf(f.w);
    *(ushort4*)(x_bf + i) = o;
  } else if (bid < NB_CVT + NB_T1) {
    int b2 = bid - NB_CVT;
    transpose_tile(w_qkv, wqkvT, Dm, N3, b2 % (N3 / 32), b2 / (N3 / 32), tid);
  } else {
    int b3 = bid - NB_CVT - NB_T1;
    transpose_tile(w_out, woutT, Dm, Dm, b3 % (Dm / 32), b3 / (Dm / 32), tid);
  }
}

// ---------------- 256x256 8-phase GEMM, single barrier/phase (R17, kept) ----------------

#define RA(buf, half) ((buf) * 65536 + (half) * 16384)
#define RB(buf, half) ((buf) * 65536 + 32768 + (half) * 16384)

#define BARRIER() __builtin_amdgcn_s_barrier()
#define SCHEDB() __builtin_amdgcn_sched_barrier(0)
#define LGK0() { asm volatile("s_waitcnt lgkmcnt(0)" ::: "memory"); __builtin_amdgcn_sched_barrier(0); }
#define VMC0() { asm volatile("s_waitcnt vmcnt(0)" ::: "memory"); __builtin_amdgcn_sched_barrier(0); }

template <int BUF, int QUAD>
DEVFN void ldAq(const char* lds, int wm, int lrow, int lkg, bf16x8 af[4][2]) {
  const char* base = lds + RA(BUF, 0) + wm * 16384;
  const int sw = (lrow & 7) << 4;
#pragma unroll
  for (int mi = 0; mi < 4; mi++) {
    int row = QUAD * 64 + mi * 16 + lrow;
#pragma unroll
    for (int kk = 0; kk < 2; kk++)
      af[mi][kk] = *(const bf16x8*)(base + row * 128 + ((kk * 64 + lkg * 16) ^ sw));
  }
}

template <int BUF, int NS>
DEVFN void ldB(const char* lds, int wn, int lrow, int lkg, bf16x8 b[2][2]) {
  const char* base = lds + RB(BUF, 0) + (wn >> 1) * 16384;
  const int sw = (lrow & 7) << 4;
#pragma unroll
  for (int ni = 0; ni < 2; ni++) {
    int row = (wn & 1) * 64 + NS * 32 + ni * 16 + lrow;
#pragma unroll
    for (int kk = 0; kk < 2; kk++)
      b[ni][kk] = *(const bf16x8*)(base + row * 128 + ((kk * 64 + lkg * 16) ^ sw));
  }
}

template <int MS, int NS>
DEVFN void mmq(f32x4 acc[8][4], bf16x8 af[4][2], bf16x8 b[2][2]) {
  __builtin_amdgcn_s_setprio(1);
#pragma unroll
  for (int kk = 0; kk < 2; kk++)
#pragma unroll
    for (int mi = 0; mi < 4; mi++)
#pragma unroll
      for (int ni = 0; ni < 2; ni++)
        acc[MS * 4 + mi][NS * 2 + ni] = __builtin_amdgcn_mfma_f32_16x16x32_bf16(
            af[mi][kk], b[ni][kk], acc[MS * 4 + mi][NS * 2 + ni], 0, 0, 0);
  __builtin_amdgcn_s_setprio(0);
}

template <int MODE>
__global__ __launch_bounds__(512, 2) void k_gemm(
    const u16* __restrict__ A, const u16* __restrict__ BT,
    const float* __restrict__ bias, float* __restrict__ Cf,
    u16* __restrict__ q_bf, u16* __restrict__ k_bf, u16* __restrict__ v_bfT,
    int N) {
  __shared__ __align__(16) char lds[131072];
  char* ldsc = lds;
  const int tid = threadIdx.x;
  const int wid = tid >> 6, lane = tid & 63;
  const int wm = wid >> 2, wn = wid & 3;
  const int lrow = lane & 15, lkg = lane >> 4;

  const int bid = blockIdx.x;
  const int xcd = bid & 7;
  const int i = bid >> 3;
  const int r = i & 15;
  const int j = i >> 4;
  const int tm0 = (xcd * 4 + (r >> 2)) << 8;
  const int tn0 = (j * 4 + (r & 3)) << 8;

  const int NT = KK >> 6;  // 32 K-tiles

  const int srow = tid >> 3;
  const int scol = (((tid & 7) * 16) ^ ((srow & 7) << 4)) >> 1;
  const int dstoff = (tid & ~63) * 16;
  const u16* bA0 = A + (size_t)(tm0 + srow) * KK + scol;
  const u16* bA1 = A + (size_t)(tm0 + 128 + srow) * KK + scol;
  const u16* bB0 = BT + (size_t)(tn0 + srow) * KK + scol;
  const u16* bB1 = BT + (size_t)(tn0 + 128 + srow) * KK + scol;

  auto stage2 = [&](const u16* src, int region) {
    async16(src, ldsc + region + dstoff);
    async16(src + (size_t)64 * KK, ldsc + region + 8192 + dstoff);
  };

  f32x4 acc[8][4] = {};
  bf16x8 afA[4][2], afB[4][2], b0[2][2], b1[2][2];

  stage2(bA0, RA(0, 0));
  stage2(bA1, RA(0, 1));
  stage2(bB0, RB(0, 0));
  stage2(bB1, RB(0, 1));
  VMC0();
  BARRIER();

  for (int it = 0; it < NT / 2; it++) {
    const int t = 2 * it;
    const int t1 = (t + 1) * 64;
    const int t2 = (t + 2 < NT) ? (t + 2) * 64 : 0;

    ldAq<0, 0>(ldsc, wm, lrow, lkg, afA);
    ldB<0, 0>(ldsc, wn, lrow, lkg, b0);
    stage2(bA0 + t1, RA(1, 0));
    stage2(bB0 + t1, RB(1, 0));
    SCHEDB();
    BARRIER(); LGK0();
    mmq<0, 0>(acc, afA, b0);

    ldB<0, 1>(ldsc, wn, lrow, lkg, b1);
    stage2(bA1 + t1, RA(1, 1));
    stage2(bB1 + t1, RB(1, 1));
    SCHEDB();
    BARRIER(); LGK0();
    mmq<0, 1>(acc, afA, b1);

    ldAq<0, 1>(ldsc, wm, lrow, lkg, afB);
    SCHEDB();
    BARRIER(); LGK0();
    mmq<1, 1>(acc, afB, b1);

    VMC0();
    BARRIER();
    mmq<1, 0>(acc, afB, b0);

    ldAq<1, 0>(ldsc, wm, lrow, lkg, afA);
    ldB<1, 0>(ldsc, wn, lrow, lkg, b0);
    stage2(bA0 + t2, RA(0, 0));
    stage2(bB0 + t2, RB(0, 0));
    SCHEDB();
    BARRIER(); LGK0();
    mmq<0, 0>(acc, afA, b0);

    ldB<1, 1>(ldsc, wn, lrow, lkg, b1);
    stage2(bA1 + t2, RA(0, 1));
    stage2(bB1 + t2, RB(0, 1));
    SCHEDB();
    BARRIER(); LGK0();
    mmq<0, 1>(acc, afA, b1);

    ldAq<1, 1>(ldsc, wm, lrow, lkg, afB);
    SCHEDB();
    BARRIER(); LGK0();
    mmq<1, 1>(acc, afB, b1);

    VMC0();
    BARRIER();
    mmq<1, 0>(acc, afB, b0);
  }

  if (MODE == 0) {
#pragma unroll
    for (int mig = 0; mig < 8; mig++) {
      int row = tm0 + wm * 128 + (mig >> 2) * 64 + (mig & 3) * 16 + lkg * 4;
#pragma unroll
      for (int nig = 0; nig < 4; nig++) {
        int col = tn0 + wn * 64 + (nig >> 1) * 32 + (nig & 1) * 16 + lrow;
        float bv = bias[col];
#pragma unroll
        for (int r2 = 0; r2 < 4; r2++)
          Cf[(size_t)(row + r2) * N + col] = acc[mig][nig][r2] + bv;
      }
    }
  } else {
#pragma unroll
    for (int mig = 0; mig < 8; mig++) {
      int row = tm0 + wm * 128 + (mig >> 2) * 64 + (mig & 3) * 16 + lkg * 4;
#pragma unroll
      for (int nig = 0; nig < 4; nig++) {
        int n = tn0 + wn * 64 + (nig >> 1) * 32 + (nig & 1) * 16 + lrow;
        float bv = bias[n];
        int type = n >> 11;
        int d = n & 2047;
        int h = d >> 7, dh = d & 127;
#pragma unroll
        for (int r2 = 0; r2 < 4; r2++) {
          int rr = row + r2;
          int b = rr >> 11, s = rr & 2047;
          float val = acc[mig][nig][r2] + bv;
          size_t idx = ((size_t)(b * H + h) * S + s) * DH + dh;
          if (type == 0) {
            q_bf[idx] = f2bf(val * ATTN_SCALE);
          } else if (type == 1) {
            Cf[(size_t)M * Dm + idx] = val;
            k_bf[idx] = f2bf(val);
          } else {
            Cf[(size_t)2 * M * Dm + idx] = val;
            v_bfT[((size_t)(b * H + h) * DH + dh) * S + s] = f2bf(val);
          }
        }
      }
    }
  }
}

// ---------------- causal flash attention: no V-LDS, 3 blocks/CU ----------------
// R18: V fragments read directly from global (L2-served via XCD bh-clustering;
// per 16-lane group = 16 rows x 64B contiguous). K stays LDS-staged (dbuf).
// LDS = 32KB K + 16KB P = 48KB -> 3 blocks/CU; stage volume halves.
__global__ __launch_bounds__(256, 3) void k_attn(const u16* __restrict__ q_bf,
                                                 const u16* __restrict__ k_bf,
                                                 const u16* __restrict__ v_bfT,
                                                 u16* __restrict__ attn_bf) {
  __shared__ u16 ldsK[2][64 * 128];  // 32 KiB
  __shared__ u16 ldsP[4][32 * 64];   // 16 KiB

  const int tid = threadIdx.x;
  const int wid = tid >> 6, lane = tid & 63;
  const int lrow = lane & 15, lkg = lane >> 4;

  const int bid = blockIdx.x;          // grid = 1024
  const int xcd = bid & 7;
  const int ii = bid >> 3;
  const int bh = xcd * 8 + (ii >> 4);
  const int qi = 15 - (ii & 15);
  const int b = bh >> 4, h = bh & 15;
  const int wq0 = qi * 128 + wid * 32;
  const int swz = (lrow & 7) << 4;

  const u16* qp = q_bf + (size_t)bh * S * DH;
  const u16* kp = k_bf + (size_t)bh * S * DH;
  const u16* vp = v_bfT + (size_t)bh * DH * S;

  bf16x8 qf[2][4];
#pragma unroll
  for (int qt = 0; qt < 2; qt++)
#pragma unroll
    for (int kk = 0; kk < 4; kk++)
      qf[qt][kk] = *(const bf16x8*)(qp + (size_t)(wq0 + qt * 16 + lrow) * DH +
                                    kk * 32 + lkg * 8);

  float mr[2][4], lr[2][4];
#pragma unroll
  for (int qt = 0; qt < 2; qt++)
#pragma unroll
    for (int r = 0; r < 4; r++) { mr[qt][r] = -1e30f; lr[qt][r] = 0.f; }
  f32x4 oacc[2][8] = {};

  const int nkb = qi * 2 + 2;

  // stage K only (16KB): 4 async16 per thread
  auto stage = [&](int kb, int buf) {
#pragma unroll
    for (int i = 0; i < 4; i++) {
      int L = i * 4096 + wid * 1024 + lane * 16;
      int krow = L >> 8, kch = (L >> 4) & 15;
      async16(kp + (size_t)(kb * 64 + krow) * DH + ((kch ^ (krow & 7)) * 8),
              (char*)ldsK[buf] + L);
    }
  };

  stage(0, 0);
  asm volatile("s_waitcnt vmcnt(0)" ::: "memory");
  __builtin_amdgcn_s_barrier();

  int cur = 0;
  for (int kb = 0; kb < nkb; kb++) {
    if (kb + 1 < nkb) stage(kb + 1, cur ^ 1);

    if (kb * 64 <= wq0 + 31) {
      const u16* Kc = ldsK[cur];
      f32x4 sacc[2][4] = {};
      __builtin_amdgcn_s_setprio(1);
#pragma unroll
      for (int kt = 0; kt < 4; kt++)
#pragma unroll
        for (int kk = 0; kk < 4; kk++) {
          bf16x8 kf = *(const bf16x8*)((const char*)Kc +
                        (kt * 16 + lrow) * 256 + ((kk * 64 + lkg * 16) ^ swz));
          sacc[0][kt] = __builtin_amdgcn_mfma_f32_16x16x32_bf16(qf[0][kk], kf,
                                                                sacc[0][kt], 0, 0, 0);
          sacc[1][kt] = __builtin_amdgcn_mfma_f32_16x16x32_bf16(qf[1][kk], kf,
                                                                sacc[1][kt], 0, 0, 0);
        }
      __builtin_amdgcn_s_setprio(0);

      if (kb * 64 + 63 > wq0) {
#pragma unroll
        for (int qt = 0; qt < 2; qt++)
#pragma unroll
          for (int kt = 0; kt < 4; kt++) {
            int k = kb * 64 + kt * 16 + lrow;
#pragma unroll
            for (int r = 0; r < 4; r++)
              if (k > wq0 + qt * 16 + lkg * 4 + r) sacc[qt][kt][r] = -1e30f;
          }
      }

      float pm[2][4];
#pragma unroll
      for (int qt = 0; qt < 2; qt++)
#pragma unroll
        for (int r = 0; r < 4; r++)
          pm[qt][r] = fmaxf(fmaxf(sacc[qt][0][r], sacc[qt][1][r]),
                            fmaxf(sacc[qt][2][r], sacc[qt][3][r]));
#pragma unroll
      for (int off = 1; off < 16; off <<= 1)
#pragma unroll
        for (int qt = 0; qt < 2; qt++)
#pragma unroll
          for (int r = 0; r < 4; r++)
            pm[qt][r] = fmaxf(pm[qt][r], __shfl_xor(pm[qt][r], off, 64));

      float dmax = pm[0][0] - mr[0][0];
#pragma unroll
      for (int qt = 0; qt < 2; qt++)
#pragma unroll
        for (int r = 0; r < 4; r++)
          dmax = fmaxf(dmax, pm[qt][r] - mr[qt][r]);
      if (!__all(dmax <= 8.0f)) {
        float sc[2][4];
#pragma unroll
        for (int qt = 0; qt < 2; qt++)
#pragma unroll
          for (int r = 0; r < 4; r++) {
            float mn = fmaxf(mr[qt][r], pm[qt][r]);
            sc[qt][r] = exp2f((mr[qt][r] - mn) * LOG2E);
            mr[qt][r] = mn;
            lr[qt][r] *= sc[qt][r];
          }
#pragma unroll
        for (int qt = 0; qt < 2; qt++)
#pragma unroll
          for (int nd = 0; nd < 8; nd++)
#pragma unroll
            for (int r = 0; r < 4; r++) oacc[qt][nd][r] *= sc[qt][r];
      }

      float rs[2][4] = {};
#pragma unroll
      for (int qt = 0; qt < 2; qt++)
#pragma unroll
        for (int kt = 0; kt < 4; kt++)
#pragma unroll
          for (int r = 0; r < 4; r++) {
            float p = exp2f((sacc[qt][kt][r] - mr[qt][r]) * LOG2E);
            rs[qt][r] += p;
            int prow = qt * 16 + lkg * 4 + r;
            *(u16*)((char*)ldsP[wid] + prow * 128 +
                    (((kt * 16 + lrow) * 2) ^ ((prow & 7) << 4))) = f2bf(p);
          }
#pragma unroll
      for (int off = 1; off < 16; off <<= 1)
#pragma unroll
        for (int qt = 0; qt < 2; qt++)
#pragma unroll
          for (int r = 0; r < 4; r++)
            rs[qt][r] += __shfl_xor(rs[qt][r], off, 64);
#pragma unroll
      for (int qt = 0; qt < 2; qt++)
#pragma unroll
        for (int r = 0; r < 4; r++)
          lr[qt][r] += rs[qt][r];

      asm volatile("s_waitcnt lgkmcnt(0)" ::: "memory");
      bf16x8 pf[2][2];
#pragma unroll
      for (int qt = 0; qt < 2; qt++)
#pragma unroll
        for (int kk = 0; kk < 2; kk++)
          pf[qt][kk] = *(const bf16x8*)((const char*)ldsP[wid] +
                         (qt * 16 + lrow) * 128 + ((kk * 64 + lkg * 16) ^ swz));
      __builtin_amdgcn_s_setprio(1);
#pragma unroll
      for (int nd = 0; nd < 8; nd++) {
        const u16* vrow = vp + (size_t)(nd * 16 + lrow) * S + kb * 64 + lkg * 8;
        bf16x8 vf0 = *(const bf16x8*)(vrow);
        bf16x8 vf1 = *(const bf16x8*)(vrow + 32);
#pragma unroll
        for (int qt = 0; qt < 2; qt++) {
          oacc[qt][nd] = __builtin_amdgcn_mfma_f32_16x16x32_bf16(pf[qt][0], vf0,
                                                                 oacc[qt][nd], 0, 0, 0);
          oacc[qt][nd] = __builtin_amdgcn_mfma_f32_16x16x32_bf16(pf[qt][1], vf1,
                                                                 oacc[qt][nd], 0, 0, 0);
        }
      }
      __builtin_amdgcn_s_setprio(0);
    }

    asm volatile("s_waitcnt vmcnt(0)" ::: "memory");
    __builtin_amdgcn_s_barrier();
    cur ^= 1;
  }

#pragma unroll
  for (int qt = 0; qt < 2; qt++) {
    float inv[4];
#pragma unroll
    for (int r = 0; r < 4; r++) inv[r] = 1.0f / lr[qt][r];
#pragma unroll
    for (int nd = 0; nd < 8; nd++)
#pragma unroll
      for (int r = 0; r < 4; r++) {
        int q = wq0 + qt * 16 + lkg * 4 + r;
        size_t idx = ((size_t)(b * S + q) * H + h) * DH + nd * 16 + lrow;
        attn_bf[idx] = f2bf(oacc[qt][nd][r] * inv[r]);
      }
  }
}

// ---------------- launch ----------------

extern "C" void kernel_launch(void* const* d_in, const int* in_sizes, int n_in,
                              void* d_out, int out_size, void* d_ws, size_t ws_size,
                              hipStream_t stream) {
  const float* x     = (const float*)d_in[0];
  const float* w_qkv = (const float*)d_in[1];
  const float* b_qkv = (const float*)d_in[2];
  const float* w_out = (const float*)d_in[3];
  const float* b_out = (const float*)d_in[4];
  float* out = (float*)d_out;

  char* ws = (char*)d_ws;
  u16* x_bf    = (u16*)ws; ws += (size_t)M * Dm * 2;
  u16* wqkvT   = (u16*)ws; ws += (size_t)N3 * Dm * 2;
  u16* woutT   = (u16*)ws; ws += (size_t)Dm * Dm * 2;
  u16* q_bf    = (u16*)ws; ws += (size_t)M * Dm * 2;
  u16* k_bf    = (u16*)ws; ws += (size_t)M * Dm * 2;
  u16* v_bfT   = (u16*)ws; ws += (size_t)M * Dm * 2;
  u16* attn_bf = (u16*)ws; ws += (size_t)M * Dm * 2;

  constexpr int NB_PREP = (M * Dm) / 1024 + (N3 / 32) * (Dm / 32) +
                          (Dm / 32) * (Dm / 32);  // 32768
  k_prep<<<NB_PREP, 256, 0, stream>>>(x, w_qkv, w_out, x_bf, wqkvT, woutT);

  k_gemm<1><<<(N3 / 256) * (M / 256), 512, 0, stream>>>(
      x_bf, wqkvT, b_qkv, out, q_bf, k_bf, v_bfT, N3);

  k_attn<<<S / 128 * Bb * H, 256, 0, stream>>>(q_bf, k_bf, v_bfT, attn_bf);

  k_gemm<0><<<(Dm / 256) * (M / 256), 512, 0, stream>>>(
      attn_bf, woutT, b_out, out, nullptr, nullptr, nullptr, Dm);
}

// Round 20
// 544.527 us; speedup vs baseline: 1.7283x; 1.7283x over previous
//
#include <hip/hip_runtime.h>
#include <hip/hip_bf16.h>
#include <cstdint>

typedef unsigned short u16;
typedef unsigned int u32;
typedef __attribute__((ext_vector_type(4))) float f32x4;
typedef __attribute__((ext_vector_type(8))) __bf16 bf16x8;

#define DEVFN static __device__ __forceinline__

constexpr int Bb = 4, S = 2048, Dm = 2048, H = 16, DH = 128;
constexpr int M  = Bb * S;   // 8192 rows
constexpr int N3 = 3 * Dm;   // 6144
constexpr int KK = 2048;     // K for both GEMMs
constexpr float ATTN_SCALE = 0.088388347648318447f;  // 1/sqrt(128)
constexpr float LOG2E = 1.4426950408889634f;

DEVFN u16 f2bf(float f) {
  union { float f; u32 u; } v; v.f = f;
  u32 u = v.u;
  return (u16)((u + 0x7fffu + ((u >> 16) & 1u)) >> 16);
}

DEVFN void async16(const void* g, void* l) {
  __builtin_amdgcn_global_load_lds(
      (__attribute__((address_space(1))) unsigned int*)(g),
      (__attribute__((address_space(3))) unsigned int*)(l), 16, 0, 0);
}

// ---------------- fused prep kernel ----------------

DEVFN void transpose_tile(const float* __restrict__ in, u16* __restrict__ out,
                          int R, int C, int bx, int by, int tid) {
  __shared__ float tile[32][33];
  int c0 = bx * 32, r0 = by * 32;
  int tx = tid & 31, ty = tid >> 5;  // 32 x 8
#pragma unroll
  for (int i = 0; i < 4; i++)
    tile[ty + 8 * i][tx] = in[(size_t)(r0 + ty + 8 * i) * C + c0 + tx];
  __syncthreads();
  int tx2 = (tid & 7) * 4, ty2 = tid >> 3;
  ushort4 o;
  o.x = f2bf(tile[tx2 + 0][ty2]);
  o.y = f2bf(tile[tx2 + 1][ty2]);
  o.z = f2bf(tile[tx2 + 2][ty2]);
  o.w = f2bf(tile[tx2 + 3][ty2]);
  *(ushort4*)(&out[(size_t)(c0 + ty2) * R + r0 + tx2]) = o;
}

__global__ __launch_bounds__(256) void k_prep(
    const float* __restrict__ x, const float* __restrict__ w_qkv,
    const float* __restrict__ w_out, u16* __restrict__ x_bf,
    u16* __restrict__ wqkvT, u16* __restrict__ woutT) {
  const int bid = blockIdx.x, tid = threadIdx.x;
  constexpr int NB_CVT = (M * Dm) / 1024;            // 16384
  constexpr int NB_T1 = (N3 / 32) * (Dm / 32);       // 12288
  if (bid < NB_CVT) {
    int i = (bid * 256 + tid) * 4;
    float4 f = *(const float4*)(x + i);
    ushort4 o;
    o.x = f2bf(f.x); o.y = f2bf(f.y); o.z = f2bf(f.z); o.w = f2bf(f.w);
    *(ushort4*)(x_bf + i) = o;
  } else if (bid < NB_CVT + NB_T1) {
    int b2 = bid - NB_CVT;
    transpose_tile(w_qkv, wqkvT, Dm, N3, b2 % (N3 / 32), b2 / (N3 / 32), tid);
  } else {
    int b3 = bid - NB_CVT - NB_T1;
    transpose_tile(w_out, woutT, Dm, Dm, b3 % (Dm / 32), b3 / (Dm / 32), tid);
  }
}

// ---------------- 256x256 8-phase GEMM, single barrier/phase (R17) ----------------

#define RA(buf, half) ((buf) * 65536 + (half) * 16384)
#define RB(buf, half) ((buf) * 65536 + 32768 + (half) * 16384)

#define BARRIER() __builtin_amdgcn_s_barrier()
#define SCHEDB() __builtin_amdgcn_sched_barrier(0)
#define LGK0() { asm volatile("s_waitcnt lgkmcnt(0)" ::: "memory"); __builtin_amdgcn_sched_barrier(0); }
#define VMC0() { asm volatile("s_waitcnt vmcnt(0)" ::: "memory"); __builtin_amdgcn_sched_barrier(0); }

template <int BUF, int QUAD>
DEVFN void ldAq(const char* lds, int wm, int lrow, int lkg, bf16x8 af[4][2]) {
  const char* base = lds + RA(BUF, 0) + wm * 16384;
  const int sw = (lrow & 7) << 4;
#pragma unroll
  for (int mi = 0; mi < 4; mi++) {
    int row = QUAD * 64 + mi * 16 + lrow;
#pragma unroll
    for (int kk = 0; kk < 2; kk++)
      af[mi][kk] = *(const bf16x8*)(base + row * 128 + ((kk * 64 + lkg * 16) ^ sw));
  }
}

template <int BUF, int NS>
DEVFN void ldB(const char* lds, int wn, int lrow, int lkg, bf16x8 b[2][2]) {
  const char* base = lds + RB(BUF, 0) + (wn >> 1) * 16384;
  const int sw = (lrow & 7) << 4;
#pragma unroll
  for (int ni = 0; ni < 2; ni++) {
    int row = (wn & 1) * 64 + NS * 32 + ni * 16 + lrow;
#pragma unroll
    for (int kk = 0; kk < 2; kk++)
      b[ni][kk] = *(const bf16x8*)(base + row * 128 + ((kk * 64 + lkg * 16) ^ sw));
  }
}

template <int MS, int NS>
DEVFN void mmq(f32x4 acc[8][4], bf16x8 af[4][2], bf16x8 b[2][2]) {
  __builtin_amdgcn_s_setprio(1);
#pragma unroll
  for (int kk = 0; kk < 2; kk++)
#pragma unroll
    for (int mi = 0; mi < 4; mi++)
#pragma unroll
      for (int ni = 0; ni < 2; ni++)
        acc[MS * 4 + mi][NS * 2 + ni] = __builtin_amdgcn_mfma_f32_16x16x32_bf16(
            af[mi][kk], b[ni][kk], acc[MS * 4 + mi][NS * 2 + ni], 0, 0, 0);
  __builtin_amdgcn_s_setprio(0);
}

template <int MODE>
__global__ __launch_bounds__(512, 2) void k_gemm(
    const u16* __restrict__ A, const u16* __restrict__ BT,
    const float* __restrict__ bias, float* __restrict__ Cf,
    u16* __restrict__ q_bf, u16* __restrict__ k_bf, u16* __restrict__ v_bfT,
    int N) {
  __shared__ __align__(16) char lds[131072];
  char* ldsc = lds;
  const int tid = threadIdx.x;
  const int wid = tid >> 6, lane = tid & 63;
  const int wm = wid >> 2, wn = wid & 3;
  const int lrow = lane & 15, lkg = lane >> 4;

  const int bid = blockIdx.x;
  const int xcd = bid & 7;
  const int i = bid >> 3;
  const int r = i & 15;
  const int j = i >> 4;
  const int tm0 = (xcd * 4 + (r >> 2)) << 8;
  const int tn0 = (j * 4 + (r & 3)) << 8;

  const int NT = KK >> 6;  // 32 K-tiles

  const int srow = tid >> 3;
  const int scol = (((tid & 7) * 16) ^ ((srow & 7) << 4)) >> 1;
  const int dstoff = (tid & ~63) * 16;
  const u16* bA0 = A + (size_t)(tm0 + srow) * KK + scol;
  const u16* bA1 = A + (size_t)(tm0 + 128 + srow) * KK + scol;
  const u16* bB0 = BT + (size_t)(tn0 + srow) * KK + scol;
  const u16* bB1 = BT + (size_t)(tn0 + 128 + srow) * KK + scol;

  auto stage2 = [&](const u16* src, int region) {
    async16(src, ldsc + region + dstoff);
    async16(src + (size_t)64 * KK, ldsc + region + 8192 + dstoff);
  };

  f32x4 acc[8][4] = {};
  bf16x8 afA[4][2], afB[4][2], b0[2][2], b1[2][2];

  stage2(bA0, RA(0, 0));
  stage2(bA1, RA(0, 1));
  stage2(bB0, RB(0, 0));
  stage2(bB1, RB(0, 1));
  VMC0();
  BARRIER();

  for (int it = 0; it < NT / 2; it++) {
    const int t = 2 * it;
    const int t1 = (t + 1) * 64;
    const int t2 = (t + 2 < NT) ? (t + 2) * 64 : 0;

    ldAq<0, 0>(ldsc, wm, lrow, lkg, afA);
    ldB<0, 0>(ldsc, wn, lrow, lkg, b0);
    stage2(bA0 + t1, RA(1, 0));
    stage2(bB0 + t1, RB(1, 0));
    SCHEDB();
    BARRIER(); LGK0();
    mmq<0, 0>(acc, afA, b0);

    ldB<0, 1>(ldsc, wn, lrow, lkg, b1);
    stage2(bA1 + t1, RA(1, 1));
    stage2(bB1 + t1, RB(1, 1));
    SCHEDB();
    BARRIER(); LGK0();
    mmq<0, 1>(acc, afA, b1);

    ldAq<0, 1>(ldsc, wm, lrow, lkg, afB);
    SCHEDB();
    BARRIER(); LGK0();
    mmq<1, 1>(acc, afB, b1);

    VMC0();
    BARRIER();
    mmq<1, 0>(acc, afB, b0);

    ldAq<1, 0>(ldsc, wm, lrow, lkg, afA);
    ldB<1, 0>(ldsc, wn, lrow, lkg, b0);
    stage2(bA0 + t2, RA(0, 0));
    stage2(bB0 + t2, RB(0, 0));
    SCHEDB();
    BARRIER(); LGK0();
    mmq<0, 0>(acc, afA, b0);

    ldB<1, 1>(ldsc, wn, lrow, lkg, b1);
    stage2(bA1 + t2, RA(0, 1));
    stage2(bB1 + t2, RB(0, 1));
    SCHEDB();
    BARRIER(); LGK0();
    mmq<0, 1>(acc, afA, b1);

    ldAq<1, 1>(ldsc, wm, lrow, lkg, afB);
    SCHEDB();
    BARRIER(); LGK0();
    mmq<1, 1>(acc, afB, b1);

    VMC0();
    BARRIER();
    mmq<1, 0>(acc, afB, b0);
  }

  if (MODE == 0) {
#pragma unroll
    for (int mig = 0; mig < 8; mig++) {
      int row = tm0 + wm * 128 + (mig >> 2) * 64 + (mig & 3) * 16 + lkg * 4;
#pragma unroll
      for (int nig = 0; nig < 4; nig++) {
        int col = tn0 + wn * 64 + (nig >> 1) * 32 + (nig & 1) * 16 + lrow;
        float bv = bias[col];
#pragma unroll
        for (int r2 = 0; r2 < 4; r2++)
          Cf[(size_t)(row + r2) * N + col] = acc[mig][nig][r2] + bv;
      }
    }
  } else {
#pragma unroll
    for (int mig = 0; mig < 8; mig++) {
      int row = tm0 + wm * 128 + (mig >> 2) * 64 + (mig & 3) * 16 + lkg * 4;
#pragma unroll
      for (int nig = 0; nig < 4; nig++) {
        int n = tn0 + wn * 64 + (nig >> 1) * 32 + (nig & 1) * 16 + lrow;
        float bv = bias[n];
        int type = n >> 11;
        int d = n & 2047;
        int h = d >> 7, dh = d & 127;
#pragma unroll
        for (int r2 = 0; r2 < 4; r2++) {
          int rr = row + r2;
          int b = rr >> 11, s = rr & 2047;
          float val = acc[mig][nig][r2] + bv;
          size_t idx = ((size_t)(b * H + h) * S + s) * DH + dh;
          if (type == 0) {
            q_bf[idx] = f2bf(val * ATTN_SCALE);
          } else if (type == 1) {
            Cf[(size_t)M * Dm + idx] = val;
            k_bf[idx] = f2bf(val);
          } else {
            Cf[(size_t)2 * M * Dm + idx] = val;
            v_bfT[((size_t)(b * H + h) * DH + dh) * S + s] = f2bf(val);
          }
        }
      }
    }
  }
}

// ---------------- causal flash attention (R17: V in LDS, 2 blocks/CU) ----------------
__global__ __launch_bounds__(256, 2) void k_attn(const u16* __restrict__ q_bf,
                                                 const u16* __restrict__ k_bf,
                                                 const u16* __restrict__ v_bfT,
                                                 u16* __restrict__ attn_bf) {
  __shared__ u16 ldsK[2][64 * 128];
  __shared__ u16 ldsV[2][128 * 64];
  __shared__ u16 ldsP[4][32 * 64];   // 80 KiB total -> 2 blocks/CU

  const int tid = threadIdx.x;
  const int wid = tid >> 6, lane = tid & 63;
  const int lrow = lane & 15, lkg = lane >> 4;

  const int bid = blockIdx.x;          // grid = 1024
  const int xcd = bid & 7;
  const int ii = bid >> 3;
  const int bh = xcd * 8 + (ii >> 4);
  const int qi = 15 - (ii & 15);
  const int b = bh >> 4, h = bh & 15;
  const int wq0 = qi * 128 + wid * 32;
  const int swz = (lrow & 7) << 4;

  const u16* qp = q_bf + (size_t)bh * S * DH;
  const u16* kp = k_bf + (size_t)bh * S * DH;
  const u16* vp = v_bfT + (size_t)bh * DH * S;

  bf16x8 qf[2][4];
#pragma unroll
  for (int qt = 0; qt < 2; qt++)
#pragma unroll
    for (int kk = 0; kk < 4; kk++)
      qf[qt][kk] = *(const bf16x8*)(qp + (size_t)(wq0 + qt * 16 + lrow) * DH +
                                    kk * 32 + lkg * 8);

  float mr[2][4], lr[2][4];
#pragma unroll
  for (int qt = 0; qt < 2; qt++)
#pragma unroll
    for (int r = 0; r < 4; r++) { mr[qt][r] = -1e30f; lr[qt][r] = 0.f; }
  f32x4 oacc[2][8] = {};

  const int nkb = qi * 2 + 2;

  auto stage = [&](int kb, int buf) {
#pragma unroll
    for (int i = 0; i < 4; i++) {
      int L = i * 4096 + wid * 1024 + lane * 16;
      int krow = L >> 8, kch = (L >> 4) & 15;
      async16(kp + (size_t)(kb * 64 + krow) * DH + ((kch ^ (krow & 7)) * 8),
              (char*)ldsK[buf] + L);
      int vd = L >> 7, vch = (L >> 4) & 7;
      async16(vp + (size_t)vd * S + kb * 64 + ((vch ^ (vd & 7)) * 8),
              (char*)ldsV[buf] + L);
    }
  };

  stage(0, 0);
  asm volatile("s_waitcnt vmcnt(0)" ::: "memory");
  __builtin_amdgcn_s_barrier();

  int cur = 0;
  for (int kb = 0; kb < nkb; kb++) {
    if (kb + 1 < nkb) stage(kb + 1, cur ^ 1);

    if (kb * 64 <= wq0 + 31) {
      const u16* Kc = ldsK[cur];
      const u16* Vc = ldsV[cur];
      f32x4 sacc[2][4] = {};
      __builtin_amdgcn_s_setprio(1);
#pragma unroll
      for (int kt = 0; kt < 4; kt++)
#pragma unroll
        for (int kk = 0; kk < 4; kk++) {
          bf16x8 kf = *(const bf16x8*)((const char*)Kc +
                        (kt * 16 + lrow) * 256 + ((kk * 64 + lkg * 16) ^ swz));
          sacc[0][kt] = __builtin_amdgcn_mfma_f32_16x16x32_bf16(qf[0][kk], kf,
                                                                sacc[0][kt], 0, 0, 0);
          sacc[1][kt] = __builtin_amdgcn_mfma_f32_16x16x32_bf16(qf[1][kk], kf,
                                                                sacc[1][kt], 0, 0, 0);
        }
      __builtin_amdgcn_s_setprio(0);

      if (kb * 64 + 63 > wq0) {
#pragma unroll
        for (int qt = 0; qt < 2; qt++)
#pragma unroll
          for (int kt = 0; kt < 4; kt++) {
            int k = kb * 64 + kt * 16 + lrow;
#pragma unroll
            for (int r = 0; r < 4; r++)
              if (k > wq0 + qt * 16 + lkg * 4 + r) sacc[qt][kt][r] = -1e30f;
          }
      }

      float pm[2][4];
#pragma unroll
      for (int qt = 0; qt < 2; qt++)
#pragma unroll
        for (int r = 0; r < 4; r++)
          pm[qt][r] = fmaxf(fmaxf(sacc[qt][0][r], sacc[qt][1][r]),
                            fmaxf(sacc[qt][2][r], sacc[qt][3][r]));
#pragma unroll
      for (int off = 1; off < 16; off <<= 1)
#pragma unroll
        for (int qt = 0; qt < 2; qt++)
#pragma unroll
          for (int r = 0; r < 4; r++)
            pm[qt][r] = fmaxf(pm[qt][r], __shfl_xor(pm[qt][r], off, 64));

      float dmax = pm[0][0] - mr[0][0];
#pragma unroll
      for (int qt = 0; qt < 2; qt++)
#pragma unroll
        for (int r = 0; r < 4; r++)
          dmax = fmaxf(dmax, pm[qt][r] - mr[qt][r]);
      if (!__all(dmax <= 8.0f)) {
        float sc[2][4];
#pragma unroll
        for (int qt = 0; qt < 2; qt++)
#pragma unroll
          for (int r = 0; r < 4; r++) {
            float mn = fmaxf(mr[qt][r], pm[qt][r]);
            sc[qt][r] = exp2f((mr[qt][r] - mn) * LOG2E);
            mr[qt][r] = mn;
            lr[qt][r] *= sc[qt][r];
          }
#pragma unroll
        for (int qt = 0; qt < 2; qt++)
#pragma unroll
          for (int nd = 0; nd < 8; nd++)
#pragma unroll
            for (int r = 0; r < 4; r++) oacc[qt][nd][r] *= sc[qt][r];
      }

      float rs[2][4] = {};
#pragma unroll
      for (int qt = 0; qt < 2; qt++)
#pragma unroll
        for (int kt = 0; kt < 4; kt++)
#pragma unroll
          for (int r = 0; r < 4; r++) {
            float p = exp2f((sacc[qt][kt][r] - mr[qt][r]) * LOG2E);
            rs[qt][r] += p;
            int prow = qt * 16 + lkg * 4 + r;
            *(u16*)((char*)ldsP[wid] + prow * 128 +
                    (((kt * 16 + lrow) * 2) ^ ((prow & 7) << 4))) = f2bf(p);
          }
#pragma unroll
      for (int off = 1; off < 16; off <<= 1)
#pragma unroll
        for (int qt = 0; qt < 2; qt++)
#pragma unroll
          for (int r = 0; r < 4; r++)
            rs[qt][r] += __shfl_xor(rs[qt][r], off, 64);
#pragma unroll
      for (int qt = 0; qt < 2; qt++)
#pragma unroll
        for (int r = 0; r < 4; r++)
          lr[qt][r] += rs[qt][r];

      asm volatile("s_waitcnt lgkmcnt(0)" ::: "memory");
      bf16x8 pf[2][2];
#pragma unroll
      for (int qt = 0; qt < 2; qt++)
#pragma unroll
        for (int kk = 0; kk < 2; kk++)
          pf[qt][kk] = *(const bf16x8*)((const char*)ldsP[wid] +
                         (qt * 16 + lrow) * 128 + ((kk * 64 + lkg * 16) ^ swz));
      __builtin_amdgcn_s_setprio(1);
#pragma unroll
      for (int nd = 0; nd < 8; nd++) {
        bf16x8 vf0 = *(const bf16x8*)((const char*)Vc +
                       (nd * 16 + lrow) * 128 + ((lkg * 16) ^ swz));
        bf16x8 vf1 = *(const bf16x8*)((const char*)Vc +
                       (nd * 16 + lrow) * 128 + ((64 + lkg * 16) ^ swz));
#pragma unroll
        for (int qt = 0; qt < 2; qt++) {
          oacc[qt][nd] = __builtin_amdgcn_mfma_f32_16x16x32_bf16(pf[qt][0], vf0,
                                                                 oacc[qt][nd], 0, 0, 0);
          oacc[qt][nd] = __builtin_amdgcn_mfma_f32_16x16x32_bf16(pf[qt][1], vf1,
                                                                 oacc[qt][nd], 0, 0, 0);
        }
      }
      __builtin_amdgcn_s_setprio(0);
    }

    asm volatile("s_waitcnt vmcnt(0)" ::: "memory");
    __builtin_amdgcn_s_barrier();
    cur ^= 1;
  }

#pragma unroll
  for (int qt = 0; qt < 2; qt++) {
    float inv[4];
#pragma unroll
    for (int r = 0; r < 4; r++) inv[r] = 1.0f / lr[qt][r];
#pragma unroll
    for (int nd = 0; nd < 8; nd++)
#pragma unroll
      for (int r = 0; r < 4; r++) {
        int q = wq0 + qt * 16 + lkg * 4 + r;
        size_t idx = ((size_t)(b * S + q) * H + h) * DH + nd * 16 + lrow;
        attn_bf[idx] = f2bf(oacc[qt][nd][r] * inv[r]);
      }
  }
}

// ---------------- launch ----------------

extern "C" void kernel_launch(void* const* d_in, const int* in_sizes, int n_in,
                              void* d_out, int out_size, void* d_ws, size_t ws_size,
                              hipStream_t stream) {
  const float* x     = (const float*)d_in[0];
  const float* w_qkv = (const float*)d_in[1];
  const float* b_qkv = (const float*)d_in[2];
  const float* w_out = (const float*)d_in[3];
  const float* b_out = (const float*)d_in[4];
  float* out = (float*)d_out;

  char* ws = (char*)d_ws;
  u16* x_bf    = (u16*)ws; ws += (size_t)M * Dm * 2;
  u16* wqkvT   = (u16*)ws; ws += (size_t)N3 * Dm * 2;
  u16* woutT   = (u16*)ws; ws += (size_t)Dm * Dm * 2;
  u16* q_bf    = (u16*)ws; ws += (size_t)M * Dm * 2;
  u16* k_bf    = (u16*)ws; ws += (size_t)M * Dm * 2;
  u16* v_bfT   = (u16*)ws; ws += (size_t)M * Dm * 2;
  u16* attn_bf = (u16*)ws; ws += (size_t)M * Dm * 2;

  constexpr int NB_PREP = (M * Dm) / 1024 + (N3 / 32) * (Dm / 32) +
                          (Dm / 32) * (Dm / 32);  // 32768
  k_prep<<<NB_PREP, 256, 0, stream>>>(x, w_qkv, w_out, x_bf, wqkvT, woutT);

  k_gemm<1><<<(N3 / 256) * (M / 256), 512, 0, stream>>>(
      x_bf, wqkvT, b_qkv, out, q_bf, k_bf, v_bfT, N3);

  k_attn<<<S / 128 * Bb * H, 256, 0, stream>>>(q_bf, k_bf, v_bfT, attn_bf);

  k_gemm<0><<<(Dm / 256) * (M / 256), 512, 0, stream>>>(
      attn_bf, woutT, b_out, out, nullptr, nullptr, nullptr, Dm);
}